// Round 1
// baseline (69.514 us; speedup 1.0000x reference)
//
#include <hip/hip_runtime.h>
#include <hip/hip_bf16.h>

#define HW 512
#define CH 3

__global__ __launch_bounds__(256) void moe_conv3x3_kernel(
    const float* __restrict__ img,   // [B,3,512,512]
    const float* __restrict__ Wt,    // [E,3,3,3,3] (per-expert OIHW)
    const float* __restrict__ bias,  // [E,3]
    const int*   __restrict__ alloc, // [B]
    float*       __restrict__ out)   // [B,3,512,512]
{
    __shared__ float sw[CH][CH][3][3]; // [o][i][kh][kw]
    __shared__ float sb[CH];

    const int b   = blockIdx.y;
    const int tid = threadIdx.x;
    const int e   = alloc[b];

    if (tid < CH * CH * 9) {
        ((float*)sw)[tid] = Wt[(size_t)e * (CH * CH * 9) + tid];
    }
    if (tid < CH) sb[tid] = bias[(size_t)e * CH + tid];
    __syncthreads();

    // 65536 threads per sample: each handles 4 consecutive w pixels of one row.
    const int idx = blockIdx.x * 256 + tid;   // 0..65535
    const int w4  = (idx & 127) * 4;          // 0,4,...,508
    const int h   = idx >> 7;                 // 0..511

    const float* inb = img + (size_t)b * CH * HW * HW;

    float acc0[4], acc1[4], acc2[4];
#pragma unroll
    for (int j = 0; j < 4; ++j) { acc0[j] = sb[0]; acc1[j] = sb[1]; acc2[j] = sb[2]; }

#pragma unroll
    for (int ci = 0; ci < CH; ++ci) {
        const float* inc = inb + (size_t)ci * HW * HW;
#pragma unroll
        for (int kh = 0; kh < 3; ++kh) {
            const int hr = h + kh - 1;
            float row[6];
            if (hr >= 0 && hr < HW) {
                const float* r = inc + (size_t)hr * HW + w4;
                const float4 v = *(const float4*)r;   // w4 % 4 == 0 -> 16B aligned
                row[1] = v.x; row[2] = v.y; row[3] = v.z; row[4] = v.w;
                row[0] = (w4 > 0)        ? r[-1] : 0.0f;
                row[5] = (w4 < HW - 4)   ? r[4]  : 0.0f;
            } else {
#pragma unroll
                for (int j = 0; j < 6; ++j) row[j] = 0.0f;
            }
#pragma unroll
            for (int kw = 0; kw < 3; ++kw) {
                const float w0 = sw[0][ci][kh][kw];
                const float w1 = sw[1][ci][kh][kw];
                const float w2 = sw[2][ci][kh][kw];
#pragma unroll
                for (int j = 0; j < 4; ++j) {
                    const float x = row[j + kw];
                    acc0[j] = fmaf(x, w0, acc0[j]);
                    acc1[j] = fmaf(x, w1, acc1[j]);
                    acc2[j] = fmaf(x, w2, acc2[j]);
                }
            }
        }
    }

    float* ob = out + (size_t)b * CH * HW * HW + (size_t)h * HW + w4;
    *(float4*)(ob)               = make_float4(acc0[0], acc0[1], acc0[2], acc0[3]);
    *(float4*)(ob + HW * HW)     = make_float4(acc1[0], acc1[1], acc1[2], acc1[3]);
    *(float4*)(ob + 2 * HW * HW) = make_float4(acc2[0], acc2[1], acc2[2], acc2[3]);
}

extern "C" void kernel_launch(void* const* d_in, const int* in_sizes, int n_in,
                              void* d_out, int out_size, void* d_ws, size_t ws_size,
                              hipStream_t stream) {
    const float* img   = (const float*)d_in[0];  // [32,3,512,512]
    const float* Wt    = (const float*)d_in[1];  // [64,3,3,3,3]
    const float* bias  = (const float*)d_in[2];  // [64,3]
    const int*   alloc = (const int*)d_in[3];    // [32]
    float*       out   = (float*)d_out;          // [32,3,512,512]

    const int B = in_sizes[3];                   // 32
    dim3 grid(256, B);
    dim3 block(256);
    moe_conv3x3_kernel<<<grid, block, 0, stream>>>(img, Wt, bias, alloc, out);
}

// Round 3
// 41.021 us; speedup vs baseline: 1.6946x; 1.6946x over previous
//
#include <hip/hip_runtime.h>
#include <hip/hip_bf16.h>

#define HW 512
#define CH 3

typedef float v4f __attribute__((ext_vector_type(4)));

// Each thread: 4 output rows x 4 pixels x 3 output channels (48 outputs).
// Weights are wave-uniform (expert index readfirstlane'd) -> scalar regs.
__global__ __launch_bounds__(256) void moe_conv3x3_kernel(
    const float* __restrict__ img,   // [B,3,512,512]
    const float* __restrict__ Wt,    // [E,3,3,3,3] OIHW per expert
    const float* __restrict__ bias,  // [E,3]
    const int*   __restrict__ alloc, // [B]
    float*       __restrict__ out)   // [B,3,512,512]
{
    const int b = blockIdx.y;
    int e = alloc[b];
    e = __builtin_amdgcn_readfirstlane(e);   // force wave-uniform -> s_loads

    const float* we = Wt + (size_t)e * (CH * CH * 9);

    float bv[CH];
#pragma unroll
    for (int oc = 0; oc < CH; ++oc) bv[oc] = bias[(size_t)e * CH + oc];

    // thread -> (row-block, col-block): 128 col-blocks x 128 row-blocks per sample
    const int idx = blockIdx.x * 256 + threadIdx.x;  // 0..16383
    const int w4  = (idx & 127) * 4;                 // 0..508 step 4
    const int hb  = (idx >> 7) * 4;                  // 0..508 step 4

    const float* inb = img + (size_t)b * CH * HW * HW;

    float acc[CH][4][4];
#pragma unroll
    for (int oc = 0; oc < CH; ++oc)
#pragma unroll
        for (int r = 0; r < 4; ++r)
#pragma unroll
            for (int j = 0; j < 4; ++j) acc[oc][r][j] = bv[oc];

#pragma unroll
    for (int ci = 0; ci < CH; ++ci) {
        const float* inc = inb + (size_t)ci * HW * HW;

        // 27 uniform weights for this input channel: wk[oc][kh][kw]
        float wk[CH][3][3];
#pragma unroll
        for (int oc = 0; oc < CH; ++oc)
#pragma unroll
            for (int kh = 0; kh < 3; ++kh)
#pragma unroll
                for (int kw = 0; kw < 3; ++kw)
                    wk[oc][kh][kw] = we[((oc * CH + ci) * 3 + kh) * 3 + kw];

#pragma unroll
        for (int ri = 0; ri < 6; ++ri) {            // input rows hb-1 .. hb+4
            const int hr = hb + ri - 1;
            float row[6];
            if (hr >= 0 && hr < HW) {               // wave-uniform branch
                const float* rsrc = inc + (size_t)hr * HW + w4;
                const v4f v = *(const v4f*)rsrc;
                row[1] = v.x; row[2] = v.y; row[3] = v.z; row[4] = v.w;
                row[0] = (w4 > 0)      ? rsrc[-1] : 0.0f;
                row[5] = (w4 < HW - 4) ? rsrc[4]  : 0.0f;
            } else {
#pragma unroll
                for (int j = 0; j < 6; ++j) row[j] = 0.0f;
            }

            // input row ri contributes to output rows r with kh = ri - r in [0,2]
#pragma unroll
            for (int r = 0; r < 4; ++r) {
                const int kh = ri - r;
                if (kh >= 0 && kh < 3) {
#pragma unroll
                    for (int kw = 0; kw < 3; ++kw) {
#pragma unroll
                        for (int oc = 0; oc < CH; ++oc) {
                            const float wv = wk[oc][kh][kw];
#pragma unroll
                            for (int j = 0; j < 4; ++j)
                                acc[oc][r][j] = fmaf(row[j + kw], wv, acc[oc][r][j]);
                        }
                    }
                }
            }
        }
    }

    float* ob = out + (size_t)b * CH * HW * HW + (size_t)hb * HW + w4;
#pragma unroll
    for (int oc = 0; oc < CH; ++oc) {
#pragma unroll
        for (int r = 0; r < 4; ++r) {
            v4f v;
            v.x = acc[oc][r][0]; v.y = acc[oc][r][1];
            v.z = acc[oc][r][2]; v.w = acc[oc][r][3];
            __builtin_nontemporal_store(v,
                (v4f*)(ob + (size_t)oc * HW * HW + (size_t)r * HW));
        }
    }
}

extern "C" void kernel_launch(void* const* d_in, const int* in_sizes, int n_in,
                              void* d_out, int out_size, void* d_ws, size_t ws_size,
                              hipStream_t stream) {
    const float* img   = (const float*)d_in[0];  // [32,3,512,512]
    const float* Wt    = (const float*)d_in[1];  // [64,3,3,3,3]
    const float* bias  = (const float*)d_in[2];  // [64,3]
    const int*   alloc = (const int*)d_in[3];    // [32]
    float*       out   = (float*)d_out;          // [32,3,512,512]

    const int B = in_sizes[3];                   // 32
    dim3 grid(64, B);                            // 64 blocks x 256 thr = 16384 thr/sample
    dim3 block(256);
    moe_conv3x3_kernel<<<grid, block, 0, stream>>>(img, Wt, bias, alloc, out);
}